// Round 19
// baseline (267.447 us; speedup 1.0000x reference)
//
#include <hip/hip_runtime.h>

// SinkhornAttention: b=4,h=8,t=8192,dh=64, BUCKETS=64, bucket size 128.
// SINGLE fused kernel: bucket sums (own bucket only) + sortnet + attention.
// Round-2-proven MFMA dataflow: S^T = mfma(K_afrag, Q_bfrag), P via
// cvt_pk+permlane32_swap, O = mfma(P_afrag, VT_bfrag). Fixed-shift softmax.
// Round-19 = round-13 body (best, 66.8us) wrapped in a NO-PREFETCH 2-bucket
// loop, grid 1024: one resident generation (4 blocks/CU), halved ramp/tail,
// doubled per-CU phase diversity. Unlike r12/r16 there is NO register state
// held across buckets (r12: 128-cap spill; r16: 184 regs -> occupancy 11%).
// r18 lesson: gfx950 VGPR/AGPR file is UNIFIED -- AGPR offload cannot reduce
// the register budget. Tripwires: VGPR<=112, WRITE_SIZE==65536.

#define T_TOK 8192
// 512^-0.5 * log2(e): fold into Q so logits land in exp2 domain.
#define CQ (0.04419417382415922f * 1.4426950408889634f)
#define FIXED_M 12.0f

// LDS layout (38400 B total, reused across the two buckets):
#define KB_OFF 0       // 16 KB: K-half bf16 [128 tok][64 d], byte ^((row&7)<<4)
#define VT_OFF 16384   // 16 KB: V-half^T bf16 [64 d][128 tok], byte ^((d&15)<<4)
#define XB_OFF 32768   // 512 B: x[128] f32 (q-sums 0..63, k-sums 64..127)
#define QP_OFF 33280   // 1 KB: qpart[4 waves][64 d]
#define KP_OFF 34304   // 4 KB: kpart[256 threads] float4

typedef __attribute__((ext_vector_type(16))) float f32x16;
typedef __attribute__((ext_vector_type(8))) short bf16x8;

__device__ __forceinline__ unsigned cvtpk(float lo, float hi) {
  unsigned r;
  asm("v_cvt_pk_bf16_f32 %0, %1, %2" : "=v"(r) : "v"(lo), "v"(hi));
  return r;
}
__device__ __forceinline__ float exp2v(float x) {
  float r;
  asm("v_exp_f32 %0, %1\n\ts_nop 0" : "=v"(r) : "v"(x));
  return r;
}

// One 32-token attention tile vs the CURRENT half-buffers. TLOC in 0..3.
// T5: raise wave priority through the MFMA/softmax cluster.
#define ATTN_TILE(TLOC, VUHALF)                                                \
  {                                                                            \
    int tokr = (TLOC) * 32 + ln;                                               \
    f32x16 acc;                                                                \
    _Pragma("unroll") for (int r = 0; r < 16; ++r) acc[r] = 0.f;               \
    __builtin_amdgcn_s_setprio(1);                                             \
    _Pragma("unroll") for (int sl = 0; sl < 4; ++sl) {                         \
      int addr =                                                               \
          KB_OFF + tokr * 128 + ((sl * 32 + lhi * 16) ^ ((tokr & 7) << 4));    \
      bf16x8 af = *reinterpret_cast<const bf16x8*>(smem + addr);               \
      acc = __builtin_amdgcn_mfma_f32_32x32x16_bf16(af, qf[sl], acc, 0, 0, 0); \
    }                                                                          \
    _Pragma("unroll") for (int r = 0; r < 16; ++r) {                           \
      float lg = (VUHALF) ? acc[r] * ru : acc[r];                              \
      float p = exp2v(lg - FIXED_M);                                           \
      acc[r] = p;                                                              \
      lsum += p;                                                               \
    }                                                                          \
    _Pragma("unroll") for (int ks = 0; ks < 2; ++ks) {                         \
      int r0 = 8 * ks;                                                         \
      unsigned aA, bA, aB, bB;                                                 \
      asm("v_cvt_pk_bf16_f32 %0, %1, %2"                                       \
          : "=v"(aA) : "v"(acc[r0 + 0]), "v"(acc[r0 + 1]));                    \
      asm("v_cvt_pk_bf16_f32 %0, %1, %2"                                       \
          : "=v"(bA) : "v"(acc[r0 + 2]), "v"(acc[r0 + 3]));                    \
      asm("v_cvt_pk_bf16_f32 %0, %1, %2"                                       \
          : "=v"(aB) : "v"(acc[r0 + 4]), "v"(acc[r0 + 5]));                    \
      asm("v_cvt_pk_bf16_f32 %0, %1, %2"                                       \
          : "=v"(bB) : "v"(acc[r0 + 6]), "v"(acc[r0 + 7]));                    \
      asm("s_nop 1\n\tv_permlane32_swap_b32 %0, %1\n\ts_nop 1"                 \
          : "+v"(aA), "+v"(aB));                                               \
      asm("s_nop 1\n\tv_permlane32_swap_b32 %0, %1\n\ts_nop 1"                 \
          : "+v"(bA), "+v"(bB));                                               \
      union { unsigned uu[4]; bf16x8 f; } pf;                                  \
      pf.uu[0] = aA; pf.uu[1] = bA; pf.uu[2] = aB; pf.uu[3] = bB;              \
      int t2 = 2 * ((TLOC) * 32 + ks * 16 + lhi * 8);                          \
      {                                                                        \
        int d = ln;                                                            \
        int addr = VT_OFF + d * 256 + (t2 ^ ((d & 15) << 4));                  \
        bf16x8 vf = *reinterpret_cast<const bf16x8*>(smem + addr);             \
        o0 = __builtin_amdgcn_mfma_f32_32x32x16_bf16(pf.f, vf, o0, 0, 0, 0);   \
      }                                                                        \
      {                                                                        \
        int d = 32 + ln;                                                       \
        int addr = VT_OFF + d * 256 + (t2 ^ ((d & 15) << 4));                  \
        bf16x8 vf = *reinterpret_cast<const bf16x8*>(smem + addr);             \
        o1 = __builtin_amdgcn_mfma_f32_32x32x16_bf16(pf.f, vf, o1, 0, 0, 0);   \
      }                                                                        \
    }                                                                          \
    __builtin_amdgcn_s_setprio(0);                                             \
  }

// grid 1024, block 256 (4 waves). Wave w owns Q rows [32w,32w+32).
// Block P processes buckets 2P and 2P+1 (same bhi), sequentially, with NO
// register state carried across buckets.
__global__ __launch_bounds__(256, 2) void k3_attn(
    const float* __restrict__ q, const float* __restrict__ k,
    const float* __restrict__ v, const float* __restrict__ W,
    float* __restrict__ out) {
  __shared__ unsigned char smem[38400];

  int L = blockIdx.x;
  int P = ((L & 7) << 7) | (L >> 3);  // XCD swizzle (1024 % 8 == 0)
  int bhi = P >> 5;
  int u0 = (2 * P) & 63;
  int tid = threadIdx.x;
  int l = tid & 63;
  int w = tid >> 6;
  int lhi = l >> 5;
  int ln = l & 31;
  int hh = bhi & 7;

  const float* kb = k + (size_t)bhi * (T_TOK * 64);
  const float* vb = v + (size_t)bhi * (T_TOK * 64);
  int c4 = tid & 15;
  int tp = tid >> 2;  // 0..63 token-pair (V staging)

  for (int bkt = 0; bkt < 2; ++bkt) {
    int u = u0 + bkt;

    // ======== PHASE 0: issue ALL 24 loads in one burst (24-deep MLP) ========
    const float* qrow =
        q + ((size_t)bhi * T_TOK + (size_t)u * 128 + w * 32 + ln) * 64;
    float4 qld[8];
    #pragma unroll
    for (int sl = 0; sl < 4; ++sl) {
      qld[2 * sl] = *reinterpret_cast<const float4*>(qrow + sl * 16 + lhi * 8);
      qld[2 * sl + 1] =
          *reinterpret_cast<const float4*>(qrow + sl * 16 + lhi * 8 + 4);
    }
    float4 kld[8];
    #pragma unroll
    for (int it = 0; it < 8; ++it) {
      int row = (tid >> 4) + it * 16;  // 0..127
      kld[it] = *reinterpret_cast<const float4*>(
          kb + (size_t)(u * 128 + row) * 64 + c4 * 4);
    }
    float4 vld[8];
    {
      const float* s0 = vb + ((size_t)(u * 128 + 2 * tp)) * 64 + (tid & 3) * 4;
      #pragma unroll
      for (int i = 0; i < 4; ++i) {
        vld[i] = *reinterpret_cast<const float4*>(s0 + i * 16);
        vld[4 + i] = *reinterpret_cast<const float4*>(s0 + i * 16 + 64);
      }
    }

    // ---- process Q: frags + q-sums ----
    bf16x8 qf[4];
    float qs[32];
    #pragma unroll
    for (int sl = 0; sl < 4; ++sl) {
      float4 a4 = qld[2 * sl], b4 = qld[2 * sl + 1];
      qs[sl * 8 + 0] = a4.x; qs[sl * 8 + 1] = a4.y;
      qs[sl * 8 + 2] = a4.z; qs[sl * 8 + 3] = a4.w;
      qs[sl * 8 + 4] = b4.x; qs[sl * 8 + 5] = b4.y;
      qs[sl * 8 + 6] = b4.z; qs[sl * 8 + 7] = b4.w;
      union { unsigned uu[4]; bf16x8 f; } qu;
      qu.uu[0] = cvtpk(a4.x * CQ, a4.y * CQ);
      qu.uu[1] = cvtpk(a4.z * CQ, a4.w * CQ);
      qu.uu[2] = cvtpk(b4.x * CQ, b4.y * CQ);
      qu.uu[3] = cvtpk(b4.z * CQ, b4.w * CQ);
      qf[sl] = qu.f;
    }
    #pragma unroll
    for (int off = 1; off < 32; off <<= 1) {
      #pragma unroll
      for (int j = 0; j < 32; ++j) qs[j] += __shfl_xor(qs[j], off, 64);
    }
    if (ln == 0) {
      float* qp = (float*)(smem + QP_OFF) + w * 64 + lhi * 8;
      #pragma unroll
      for (int sl = 0; sl < 4; ++sl) {
        #pragma unroll
        for (int j = 0; j < 8; ++j) qp[sl * 16 + j] = qs[sl * 8 + j];
      }
    }

    // ---- process K: ksum + LDS ----
    float4 ksum = make_float4(0.f, 0.f, 0.f, 0.f);
    #pragma unroll
    for (int it = 0; it < 8; ++it) {
      float4 val = kld[it];
      ksum.x += val.x; ksum.y += val.y; ksum.z += val.z; ksum.w += val.w;
      int row = (tid >> 4) + it * 16;
      int addr = KB_OFF + row * 128 + ((c4 * 8) ^ ((row & 7) << 4));
      *reinterpret_cast<uint2*>(smem + addr) =
          make_uint2(cvtpk(val.x, val.y), cvtpk(val.z, val.w));
    }
    *reinterpret_cast<float4*>(smem + KP_OFF + tid * 16) = ksum;

    // ---- process V: transpose-scatter to VT ----
    #pragma unroll
    for (int i = 0; i < 4; ++i) {
      int dq = (tid & 3) + 4 * i;
      int t2 = 4 * tp;
      const float* fa = (const float*)&vld[i];
      const float* fc = (const float*)&vld[4 + i];
      #pragma unroll
      for (int jj = 0; jj < 4; ++jj) {
        int d = dq * 4 + jj;
        int addr = VT_OFF + d * 256 + (t2 ^ ((d & 15) << 4));
        *reinterpret_cast<unsigned*>(smem + addr) = cvtpk(fa[jj], fc[jj]);
      }
    }

    __syncthreads();  // B1: partial sums + own K/V staging visible

    // ---- x reduce (128 threads: 0-63 q-sums, 64-127 k-sums) ----
    if (tid < 128) {
      float* xbw = (float*)(smem + XB_OFF);
      if (tid < 64) {
        const float* qp = (const float*)(smem + QP_OFF);
        xbw[tid] = qp[tid] + qp[64 + tid] + qp[128 + tid] + qp[192 + tid];
      } else {
        int d = tid - 64;
        const float* kp = (const float*)(smem + KP_OFF);
        float xk = 0.f;
        #pragma unroll
        for (int g = 0; g < 16; ++g)
          xk += kp[(g * 16 + (d >> 2)) * 4 + (d & 3)];
        xbw[64 + d] = xk;
      }
    }
    __syncthreads();  // B2: x visible

    // ---- sortnet, per-wave redundant; 4 independent fmaf chains ----
    const float* xb = (const float*)(smem + XB_OFF);
    const float* wcol = W + (size_t)hh * 8192 + l;
    float a0 = 0.f, a1 = 0.f, a2 = 0.f, a3 = 0.f;
    #pragma unroll
    for (int kk = 0; kk < 128; kk += 4) {
      a0 = fmaf(xb[kk + 0], wcol[(size_t)(kk + 0) * 64], a0);
      a1 = fmaf(xb[kk + 1], wcol[(size_t)(kk + 1) * 64], a1);
      a2 = fmaf(xb[kk + 2], wcol[(size_t)(kk + 2) * 64], a2);
      a3 = fmaf(xb[kk + 3], wcol[(size_t)(kk + 3) * 64], a3);
    }
    float a = fmaxf((a0 + a1) + (a2 + a3), 0.f);
    float bvv = a; int bi = l;
    #pragma unroll
    for (int off = 1; off < 64; off <<= 1) {
      float ov = __shfl_xor(bvv, off, 64);
      int oi = __shfl_xor(bi, off, 64);
      if (ov > bvv || (ov == bvv && oi < bi)) { bvv = ov; bi = oi; }
    }
    float e = __expf(a - bvv);
    #pragma unroll
    for (int off = 1; off < 64; off <<= 1) e += __shfl_xor(e, off, 64);
    int vu = bi;          // identical across wave
    float ru = 1.f / e;   // softmax value at argmax

    // ---- T14 async-STAGE: issue K[vu], V[vu] loads into registers NOW ----
    float4 kvu[8];
    #pragma unroll
    for (int it = 0; it < 8; ++it) {
      int row = (tid >> 4) + it * 16;
      kvu[it] = *reinterpret_cast<const float4*>(
          kb + (size_t)(vu * 128 + row) * 64 + c4 * 4);
    }
    float4 vvu[8];
    {
      const float* s0 =
          vb + ((size_t)(vu * 128 + 2 * tp)) * 64 + (tid & 3) * 4;
      #pragma unroll
      for (int i = 0; i < 4; ++i) {
        vvu[i] = *reinterpret_cast<const float4*>(s0 + i * 16);
        vvu[4 + i] = *reinterpret_cast<const float4*>(s0 + i * 16 + 64);
      }
    }

    // ---- own-half tiles while vu loads are in flight ----
    f32x16 o0, o1;
    #pragma unroll
    for (int r = 0; r < 16; ++r) { o0[r] = 0.f; o1[r] = 0.f; }
    float lsum = 0.f;

    #pragma unroll
    for (int t8 = 0; t8 < 4; ++t8) ATTN_TILE(t8, false)

    __syncthreads();  // B3: all waves done reading own K/V halves

    // ---- overwrite buffers with vu halves (registers -> LDS) ----
    #pragma unroll
    for (int it = 0; it < 8; ++it) {
      int row = (tid >> 4) + it * 16;
      int addr = KB_OFF + row * 128 + ((c4 * 8) ^ ((row & 7) << 4));
      *reinterpret_cast<uint2*>(smem + addr) =
          make_uint2(cvtpk(kvu[it].x, kvu[it].y), cvtpk(kvu[it].z, kvu[it].w));
    }
    #pragma unroll
    for (int i = 0; i < 4; ++i) {
      int dq = (tid & 3) + 4 * i;
      int t2 = 4 * tp;
      const float* fa = (const float*)&vvu[i];
      const float* fc = (const float*)&vvu[4 + i];
      #pragma unroll
      for (int jj = 0; jj < 4; ++jj) {
        int d = dq * 4 + jj;
        int addr = VT_OFF + d * 256 + (t2 ^ ((d & 15) << 4));
        *reinterpret_cast<unsigned*>(smem + addr) =
            cvtpk(fa[jj] * ru, fc[jj] * ru);
      }
    }
    __syncthreads();  // B4: vu halves visible

    // ---- vu-half tiles ----
    #pragma unroll
    for (int t8 = 0; t8 < 4; ++t8) ATTN_TILE(t8, true)

    // ---- epilogue: combine lsum; distribute inv per q-row; store ----
    lsum += __shfl_xor(lsum, 32, 64);
    float inv = 1.f / lsum;
    float* ob = out + ((size_t)bhi * T_TOK + (size_t)u * 128 + w * 32) * 64;
    #pragma unroll
    for (int r = 0; r < 16; ++r) {
      int row = (r & 3) + 8 * (r >> 2) + 4 * lhi;
      float invr = __shfl(inv, row, 64);
      ob[(size_t)row * 64 + ln] = o0[r] * invr;
      ob[(size_t)row * 64 + 32 + ln] = o1[r] * invr;
    }

    if (bkt == 0) __syncthreads();  // seam: LDS free for next bucket's staging
  }
}

extern "C" void kernel_launch(void* const* d_in, const int* in_sizes, int n_in,
                              void* d_out, int out_size, void* d_ws, size_t ws_size,
                              hipStream_t stream) {
  const float* q = (const float*)d_in[0];
  const float* k = (const float*)d_in[1];
  const float* v = (const float*)d_in[2];
  const float* W = (const float*)d_in[3];
  float* out = (float*)d_out;

  hipLaunchKernelGGL(k3_attn, dim3(1024), dim3(256), 0, stream, q, k, v, W, out);
}

// Round 20
// 66.803 us; speedup vs baseline: 4.0035x; 4.0035x over previous
//
#include <hip/hip_runtime.h>

// SinkhornAttention: b=4,h=8,t=8192,dh=64, BUCKETS=64, bucket size 128.
// SINGLE fused kernel: bucket sums (own bucket only) + sortnet + attention.
// Round-2-proven MFMA dataflow: S^T = mfma(K_afrag, Q_bfrag), P via
// cvt_pk+permlane32_swap, O = mfma(P_afrag, VT_bfrag). Fixed-shift softmax.
// Round-20 = round-13 VERBATIM (verified best, 66.8us).
// Excluded with counter evidence (do not retry):
//   r12/r16/r19: cross-bucket pipelining/looping -> spill (128-cap) or
//                occupancy collapse (184 VGPR -> 11%); body needs ~104 live.
//   r15/r17: launch_bounds 4/3 -> compiler clamps to 64/84 and spills.
//   r18: AGPR offload -> unified VGPR/AGPR file on gfx950, no budget gain.
//   r14: dbuf+staggered-sleep -> negative (barrier not binding; sleep idle).
// Regime: latency-bound at 2 waves/EU, L3-resident working set; the
// remaining ~2x over the latency floor is walled off by the register bands.

#define T_TOK 8192
// 512^-0.5 * log2(e): fold into Q so logits land in exp2 domain.
#define CQ (0.04419417382415922f * 1.4426950408889634f)
#define FIXED_M 12.0f

// LDS layout (38400 B total):
#define KB_OFF 0       // 16 KB: K-half bf16 [128 tok][64 d], byte ^((row&7)<<4)
#define VT_OFF 16384   // 16 KB: V-half^T bf16 [64 d][128 tok], byte ^((d&15)<<4)
#define XB_OFF 32768   // 512 B: x[128] f32 (q-sums 0..63, k-sums 64..127)
#define QP_OFF 33280   // 1 KB: qpart[4 waves][64 d]
#define KP_OFF 34304   // 4 KB: kpart[256 threads] float4

typedef __attribute__((ext_vector_type(16))) float f32x16;
typedef __attribute__((ext_vector_type(8))) short bf16x8;

__device__ __forceinline__ unsigned cvtpk(float lo, float hi) {
  unsigned r;
  asm("v_cvt_pk_bf16_f32 %0, %1, %2" : "=v"(r) : "v"(lo), "v"(hi));
  return r;
}
__device__ __forceinline__ float exp2v(float x) {
  float r;
  asm("v_exp_f32 %0, %1\n\ts_nop 0" : "=v"(r) : "v"(x));
  return r;
}

// One 32-token attention tile vs the CURRENT half-buffers. TLOC in 0..3.
// T5: raise wave priority through the MFMA/softmax cluster.
#define ATTN_TILE(TLOC, VUHALF)                                                \
  {                                                                            \
    int tokr = (TLOC) * 32 + ln;                                               \
    f32x16 acc;                                                                \
    _Pragma("unroll") for (int r = 0; r < 16; ++r) acc[r] = 0.f;               \
    __builtin_amdgcn_s_setprio(1);                                             \
    _Pragma("unroll") for (int sl = 0; sl < 4; ++sl) {                         \
      int addr =                                                               \
          KB_OFF + tokr * 128 + ((sl * 32 + lhi * 16) ^ ((tokr & 7) << 4));    \
      bf16x8 af = *reinterpret_cast<const bf16x8*>(smem + addr);               \
      acc = __builtin_amdgcn_mfma_f32_32x32x16_bf16(af, qf[sl], acc, 0, 0, 0); \
    }                                                                          \
    _Pragma("unroll") for (int r = 0; r < 16; ++r) {                           \
      float lg = (VUHALF) ? acc[r] * ru : acc[r];                              \
      float p = exp2v(lg - FIXED_M);                                           \
      acc[r] = p;                                                              \
      lsum += p;                                                               \
    }                                                                          \
    _Pragma("unroll") for (int ks = 0; ks < 2; ++ks) {                         \
      int r0 = 8 * ks;                                                         \
      unsigned aA, bA, aB, bB;                                                 \
      asm("v_cvt_pk_bf16_f32 %0, %1, %2"                                       \
          : "=v"(aA) : "v"(acc[r0 + 0]), "v"(acc[r0 + 1]));                    \
      asm("v_cvt_pk_bf16_f32 %0, %1, %2"                                       \
          : "=v"(bA) : "v"(acc[r0 + 2]), "v"(acc[r0 + 3]));                    \
      asm("v_cvt_pk_bf16_f32 %0, %1, %2"                                       \
          : "=v"(aB) : "v"(acc[r0 + 4]), "v"(acc[r0 + 5]));                    \
      asm("v_cvt_pk_bf16_f32 %0, %1, %2"                                       \
          : "=v"(bB) : "v"(acc[r0 + 6]), "v"(acc[r0 + 7]));                    \
      asm("s_nop 1\n\tv_permlane32_swap_b32 %0, %1\n\ts_nop 1"                 \
          : "+v"(aA), "+v"(aB));                                               \
      asm("s_nop 1\n\tv_permlane32_swap_b32 %0, %1\n\ts_nop 1"                 \
          : "+v"(bA), "+v"(bB));                                               \
      union { unsigned uu[4]; bf16x8 f; } pf;                                  \
      pf.uu[0] = aA; pf.uu[1] = bA; pf.uu[2] = aB; pf.uu[3] = bB;              \
      int t2 = 2 * ((TLOC) * 32 + ks * 16 + lhi * 8);                          \
      {                                                                        \
        int d = ln;                                                            \
        int addr = VT_OFF + d * 256 + (t2 ^ ((d & 15) << 4));                  \
        bf16x8 vf = *reinterpret_cast<const bf16x8*>(smem + addr);             \
        o0 = __builtin_amdgcn_mfma_f32_32x32x16_bf16(pf.f, vf, o0, 0, 0, 0);   \
      }                                                                        \
      {                                                                        \
        int d = 32 + ln;                                                       \
        int addr = VT_OFF + d * 256 + (t2 ^ ((d & 15) << 4));                  \
        bf16x8 vf = *reinterpret_cast<const bf16x8*>(smem + addr);             \
        o1 = __builtin_amdgcn_mfma_f32_32x32x16_bf16(pf.f, vf, o1, 0, 0, 0);   \
      }                                                                        \
    }                                                                          \
    __builtin_amdgcn_s_setprio(0);                                             \
  }

// grid 2048, block 256 (4 waves). Wave w owns Q rows [32w,32w+32).
__global__ __launch_bounds__(256, 2) void k3_attn(
    const float* __restrict__ q, const float* __restrict__ k,
    const float* __restrict__ v, const float* __restrict__ W,
    float* __restrict__ out) {
  __shared__ unsigned char smem[38400];

  int L = blockIdx.x;
  int G = ((L & 7) << 8) | (L >> 3);  // XCD swizzle (2048 % 8 == 0)
  int bhi = G >> 6, u = G & 63;
  int tid = threadIdx.x;
  int l = tid & 63;
  int w = tid >> 6;
  int lhi = l >> 5;
  int ln = l & 31;
  int hh = bhi & 7;

  const float* kb = k + (size_t)bhi * (T_TOK * 64);
  const float* vb = v + (size_t)bhi * (T_TOK * 64);
  int c4 = tid & 15;
  int tp = tid >> 2;  // 0..63 token-pair (V staging)

  // ======== PHASE 0: issue ALL 24 loads in one burst (24-deep MLP) ========
  const float* qrow = q + ((size_t)bhi * T_TOK + (size_t)u * 128 + w * 32 + ln) * 64;
  float4 qld[8];
  #pragma unroll
  for (int sl = 0; sl < 4; ++sl) {
    qld[2 * sl] = *reinterpret_cast<const float4*>(qrow + sl * 16 + lhi * 8);
    qld[2 * sl + 1] = *reinterpret_cast<const float4*>(qrow + sl * 16 + lhi * 8 + 4);
  }
  float4 kld[8];
  #pragma unroll
  for (int it = 0; it < 8; ++it) {
    int row = (tid >> 4) + it * 16;  // 0..127
    kld[it] = *reinterpret_cast<const float4*>(
        kb + (size_t)(u * 128 + row) * 64 + c4 * 4);
  }
  float4 vld[8];
  {
    const float* s0 = vb + ((size_t)(u * 128 + 2 * tp)) * 64 + (tid & 3) * 4;
    #pragma unroll
    for (int i = 0; i < 4; ++i) {
      vld[i] = *reinterpret_cast<const float4*>(s0 + i * 16);
      vld[4 + i] = *reinterpret_cast<const float4*>(s0 + i * 16 + 64);
    }
  }

  // ---- process Q: frags + q-sums (waits only on the first 8 loads) ----
  bf16x8 qf[4];
  float qs[32];
  #pragma unroll
  for (int sl = 0; sl < 4; ++sl) {
    float4 a4 = qld[2 * sl], b4 = qld[2 * sl + 1];
    qs[sl * 8 + 0] = a4.x; qs[sl * 8 + 1] = a4.y;
    qs[sl * 8 + 2] = a4.z; qs[sl * 8 + 3] = a4.w;
    qs[sl * 8 + 4] = b4.x; qs[sl * 8 + 5] = b4.y;
    qs[sl * 8 + 6] = b4.z; qs[sl * 8 + 7] = b4.w;
    union { unsigned uu[4]; bf16x8 f; } qu;
    qu.uu[0] = cvtpk(a4.x * CQ, a4.y * CQ);
    qu.uu[1] = cvtpk(a4.z * CQ, a4.w * CQ);
    qu.uu[2] = cvtpk(b4.x * CQ, b4.y * CQ);
    qu.uu[3] = cvtpk(b4.z * CQ, b4.w * CQ);
    qf[sl] = qu.f;
  }
  #pragma unroll
  for (int off = 1; off < 32; off <<= 1) {
    #pragma unroll
    for (int j = 0; j < 32; ++j) qs[j] += __shfl_xor(qs[j], off, 64);
  }
  if (ln == 0) {
    float* qp = (float*)(smem + QP_OFF) + w * 64 + lhi * 8;
    #pragma unroll
    for (int sl = 0; sl < 4; ++sl) {
      #pragma unroll
      for (int j = 0; j < 8; ++j) qp[sl * 16 + j] = qs[sl * 8 + j];
    }
  }

  // ---- process K: ksum + LDS (waits on loads 8..15) ----
  float4 ksum = make_float4(0.f, 0.f, 0.f, 0.f);
  #pragma unroll
  for (int it = 0; it < 8; ++it) {
    float4 val = kld[it];
    ksum.x += val.x; ksum.y += val.y; ksum.z += val.z; ksum.w += val.w;
    int row = (tid >> 4) + it * 16;
    int addr = KB_OFF + row * 128 + ((c4 * 8) ^ ((row & 7) << 4));
    *reinterpret_cast<uint2*>(smem + addr) =
        make_uint2(cvtpk(val.x, val.y), cvtpk(val.z, val.w));
  }
  *reinterpret_cast<float4*>(smem + KP_OFF + tid * 16) = ksum;

  // ---- process V: transpose-scatter to VT (waits on loads 16..23) ----
  #pragma unroll
  for (int i = 0; i < 4; ++i) {
    int dq = (tid & 3) + 4 * i;
    int t2 = 4 * tp;
    const float* fa = (const float*)&vld[i];
    const float* fc = (const float*)&vld[4 + i];
    #pragma unroll
    for (int jj = 0; jj < 4; ++jj) {
      int d = dq * 4 + jj;
      int addr = VT_OFF + d * 256 + (t2 ^ ((d & 15) << 4));
      *reinterpret_cast<unsigned*>(smem + addr) = cvtpk(fa[jj], fc[jj]);
    }
  }

  __syncthreads();  // B1: partial sums + own K/V staging visible

  // ---- x reduce (128 threads: 0-63 q-sums, 64-127 k-sums) ----
  if (tid < 128) {
    float* xbw = (float*)(smem + XB_OFF);
    if (tid < 64) {
      const float* qp = (const float*)(smem + QP_OFF);
      xbw[tid] = qp[tid] + qp[64 + tid] + qp[128 + tid] + qp[192 + tid];
    } else {
      int d = tid - 64;
      const float* kp = (const float*)(smem + KP_OFF);
      float xk = 0.f;
      #pragma unroll
      for (int g = 0; g < 16; ++g) xk += kp[(g * 16 + (d >> 2)) * 4 + (d & 3)];
      xbw[64 + d] = xk;
    }
  }
  __syncthreads();  // B2: x visible

  // ---- sortnet, per-wave redundant; 4 independent fmaf chains ----
  const float* xb = (const float*)(smem + XB_OFF);
  const float* wcol = W + (size_t)hh * 8192 + l;
  float a0 = 0.f, a1 = 0.f, a2 = 0.f, a3 = 0.f;
  #pragma unroll
  for (int kk = 0; kk < 128; kk += 4) {
    a0 = fmaf(xb[kk + 0], wcol[(size_t)(kk + 0) * 64], a0);
    a1 = fmaf(xb[kk + 1], wcol[(size_t)(kk + 1) * 64], a1);
    a2 = fmaf(xb[kk + 2], wcol[(size_t)(kk + 2) * 64], a2);
    a3 = fmaf(xb[kk + 3], wcol[(size_t)(kk + 3) * 64], a3);
  }
  float a = fmaxf((a0 + a1) + (a2 + a3), 0.f);
  float bvv = a; int bi = l;
  #pragma unroll
  for (int off = 1; off < 64; off <<= 1) {
    float ov = __shfl_xor(bvv, off, 64);
    int oi = __shfl_xor(bi, off, 64);
    if (ov > bvv || (ov == bvv && oi < bi)) { bvv = ov; bi = oi; }
  }
  float e = __expf(a - bvv);
  #pragma unroll
  for (int off = 1; off < 64; off <<= 1) e += __shfl_xor(e, off, 64);
  int vu = bi;          // identical across wave
  float ru = 1.f / e;   // softmax value at argmax

  // ---- T14 async-STAGE: issue K[vu], V[vu] loads into registers NOW ----
  float4 kvu[8];
  #pragma unroll
  for (int it = 0; it < 8; ++it) {
    int row = (tid >> 4) + it * 16;
    kvu[it] = *reinterpret_cast<const float4*>(
        kb + (size_t)(vu * 128 + row) * 64 + c4 * 4);
  }
  float4 vvu[8];
  {
    const float* s0 = vb + ((size_t)(vu * 128 + 2 * tp)) * 64 + (tid & 3) * 4;
    #pragma unroll
    for (int i = 0; i < 4; ++i) {
      vvu[i] = *reinterpret_cast<const float4*>(s0 + i * 16);
      vvu[4 + i] = *reinterpret_cast<const float4*>(s0 + i * 16 + 64);
    }
  }

  // ---- own-half tiles while vu loads are in flight ----
  f32x16 o0, o1;
  #pragma unroll
  for (int r = 0; r < 16; ++r) { o0[r] = 0.f; o1[r] = 0.f; }
  float lsum = 0.f;

  #pragma unroll
  for (int t8 = 0; t8 < 4; ++t8) ATTN_TILE(t8, false)

  __syncthreads();  // B3: all waves done reading own K/V halves

  // ---- overwrite buffers with vu halves (registers -> LDS) ----
  #pragma unroll
  for (int it = 0; it < 8; ++it) {
    int row = (tid >> 4) + it * 16;
    int addr = KB_OFF + row * 128 + ((c4 * 8) ^ ((row & 7) << 4));
    *reinterpret_cast<uint2*>(smem + addr) =
        make_uint2(cvtpk(kvu[it].x, kvu[it].y), cvtpk(kvu[it].z, kvu[it].w));
  }
  #pragma unroll
  for (int i = 0; i < 4; ++i) {
    int dq = (tid & 3) + 4 * i;
    int t2 = 4 * tp;
    const float* fa = (const float*)&vvu[i];
    const float* fc = (const float*)&vvu[4 + i];
    #pragma unroll
    for (int jj = 0; jj < 4; ++jj) {
      int d = dq * 4 + jj;
      int addr = VT_OFF + d * 256 + (t2 ^ ((d & 15) << 4));
      *reinterpret_cast<unsigned*>(smem + addr) = cvtpk(fa[jj] * ru, fc[jj] * ru);
    }
  }
  __syncthreads();  // B4: vu halves visible

  // ---- vu-half tiles ----
  #pragma unroll
  for (int t8 = 0; t8 < 4; ++t8) ATTN_TILE(t8, true)

  // ---- epilogue: combine lsum across half-pair; distribute inv per q-row ----
  lsum += __shfl_xor(lsum, 32, 64);
  float inv = 1.f / lsum;
  float* ob = out + ((size_t)bhi * T_TOK + (size_t)u * 128 + w * 32) * 64;
  #pragma unroll
  for (int r = 0; r < 16; ++r) {
    int row = (r & 3) + 8 * (r >> 2) + 4 * lhi;
    float invr = __shfl(inv, row, 64);
    ob[(size_t)row * 64 + ln] = o0[r] * invr;
    ob[(size_t)row * 64 + 32 + ln] = o1[r] * invr;
  }
}

extern "C" void kernel_launch(void* const* d_in, const int* in_sizes, int n_in,
                              void* d_out, int out_size, void* d_ws, size_t ws_size,
                              hipStream_t stream) {
  const float* q = (const float*)d_in[0];
  const float* k = (const float*)d_in[1];
  const float* v = (const float*)d_in[2];
  const float* W = (const float*)d_in[3];
  float* out = (float*)d_out;

  hipLaunchKernelGGL(k3_attn, dim3(2048), dim3(256), 0, stream, q, k, v, W, out);
}